// Round 2
// baseline (106.101 us; speedup 1.0000x reference)
//
#include <hip/hip_runtime.h>
#include <hip/hip_bf16.h>
#include <stdint.h>

// ---- types -----------------------------------------------------------------
typedef __bf16 bf16x8 __attribute__((ext_vector_type(8)));
typedef float  f32x4  __attribute__((ext_vector_type(4)));
typedef __attribute__((address_space(1))) const void* gptr_t;
typedef __attribute__((address_space(3))) void*       sptr_t;

#define B_ROWS 8192
#define C_CLS  1000
#define C_PAD  1024
#define P_DIM  512
#define EPS    1e-10f

// ---- workspace layout (bytes) ----------------------------------------------
// [0,       1048576)  means_bf16  [1024][512] bf16  (rows >=1000 zeroed)
// [1048576, 1052672)  m_sq        [1024] f32
#define WS_MEANS_BF 0
#define WS_MSQ      1048576

__device__ __forceinline__ float dot8(float4 a, float4 b) {
    return a.x * a.x + a.y * a.y + a.z * a.z + a.w * a.w
         + b.x * b.x + b.y * b.y + b.z * b.z + b.w * b.w;
}

// ---- kernel 1: means-only prep (256 blocks, one wave per class row) --------
// R4: the x-normalization pass (2048 blocks, ~34 MB of HBM round-trip through
// xn_bf) is fused into the gemm; only the bf16 means + m_sq remain here.
__global__ __launch_bounds__(256) void prep_means(const float* __restrict__ means,
                                                  __hip_bfloat16* __restrict__ means_bf,
                                                  float* __restrict__ m_sq) {
    const int w = threadIdx.x >> 6;
    const int l = threadIdx.x & 63;
    const int c = blockIdx.x * 4 + w;
    if (c < C_CLS) {
        const float4* mr = (const float4*)(means + (size_t)c * P_DIM);
        float4 a = mr[l * 2];
        float4 b = mr[l * 2 + 1];
        float s = dot8(a, b);
        alignas(16) __hip_bfloat16 tmp[8];
        tmp[0] = __float2bfloat16(a.x); tmp[1] = __float2bfloat16(a.y);
        tmp[2] = __float2bfloat16(a.z); tmp[3] = __float2bfloat16(a.w);
        tmp[4] = __float2bfloat16(b.x); tmp[5] = __float2bfloat16(b.y);
        tmp[6] = __float2bfloat16(b.z); tmp[7] = __float2bfloat16(b.w);
        *(uint4*)(means_bf + (size_t)c * P_DIM + l * 8) = *(const uint4*)tmp;
        #pragma unroll
        for (int off = 32; off > 0; off >>= 1) s += __shfl_down(s, off);
        if (l == 0) m_sq[c] = s;
    } else {
        uint4 z = {0u, 0u, 0u, 0u};
        *(uint4*)(means_bf + (size_t)c * P_DIM + l * 8) = z;
        if (l == 0) m_sq[c] = 0.0f;
    }
}

// ---- kernel 2 (fused): normalize x on the fly + logits ---------------------
// 64x128 tile, BK=64, 4 waves, 1024 blocks (4/CU), XCD remap (T1), LDS XOR
// swizzle (T2). R4 change: A is staged from pristine f32 x — phase 0 computes
// per-row scl = ||means[0]||/(||x_row||+EPS) (4 threads/row, quad shfl reduce,
// scl stays in-register since staging uses the same thread->row map), and the
// K-loop converts f32->bf16 into the SAME swizzled LDS layout via ds_write_b128
// (reg-staged writes may swizzle directly; global_load_lds stays for B only).
// ds_write bank check: 8 lanes per chunk-value -> 8 phases = b128 minimum.
// Per-XCD L2 set: 2 MB x-slice (f32) + 1 MB means_bf = 3 MB < 4 MB.
__global__ __launch_bounds__(256, 4) void gemm_k(const float* __restrict__ X,       // x [8192][512] f32
                                                 const __hip_bfloat16* __restrict__ Bm, // means_bf [1024][512]
                                                 const float* __restrict__ m_sq,
                                                 float* __restrict__ out) {
    __shared__ alignas(16) char lds[24576];
    __shared__ float xsq_lds[64];
    const int t   = threadIdx.x;
    const int w   = t >> 6;         // wave 0..3
    const int l   = t & 63;
    const int q   = l >> 4;         // quad 0..3
    const int m16 = l & 15;

    // XCD-aware remap: n%8 = XCD; each XCD owns 16 consecutive brows x all bcols.
    const int n_blk  = blockIdx.x;            // 0..1023
    const int xcd    = n_blk & 7;
    const int within = n_blk >> 3;            // 0..127
    const int brow   = xcd * 16 + (within & 15);   // 0..127 (64-row tiles)
    const int bcol   = within >> 4;                // 0..7   (128-col tiles)

    const int rowbase = brow * 64;

    // ---- phase 0: row sumsq, 4 threads per row (128 floats each)
    const int prow = t >> 2;        // 0..63  (this thread's A row, also used in staging)
    const int pseg = t & 3;         // 0..3
    float scl;                      // ||means[0]|| / (||x_row|| + EPS), per-thread
    {
        const float4* xr = (const float4*)(X + (size_t)(rowbase + prow) * P_DIM + pseg * 128);
        float s = 0.f;
        #pragma unroll 8
        for (int i = 0; i < 32; ++i) {
            float4 v = xr[i];
            s += v.x * v.x + v.y * v.y + v.z * v.z + v.w * v.w;
        }
        s += __shfl_xor(s, 1);      // quad reduce: all 4 lanes of the quad get the sum
        s += __shfl_xor(s, 2);
        const float norm = sqrtf(s);
        scl = sqrtf(m_sq[0]) / (norm + EPS);
        if (pseg == 0) {
            const float sn = scl * norm;        // ||xn|| as the reference computes it
            xsq_lds[prow] = sn * sn;
        }
        // no barrier needed: xsq_lds is only read in the epilogue (many barriers later)
    }

    f32x4 acc[4][2];
    #pragma unroll
    for (int i = 0; i < 4; ++i)
        #pragma unroll
        for (int j = 0; j < 2; ++j) {
            f32x4 z = {0.f, 0.f, 0.f, 0.f};
            acc[i][j] = z;
        }

    const float* Arow  = X + (size_t)(rowbase + prow) * P_DIM;
    const char*  Bbase = (const char*)Bm + (size_t)(bcol * 128) * (P_DIM * 2);

    const int swz = (m16 & 7) << 4;                         // read-side XOR
    // staging: thread covers k [pseg*16, pseg*16+16) of row prow = logical
    // chunks pseg*2, pseg*2+1; stored at chunk ^ (row&7) (matches read side).
    const int sc0 = (((pseg * 2)     ^ (prow & 7)) << 4);
    const int sc1 = (((pseg * 2 + 1) ^ (prow & 7)) << 4);
    char* const awr = lds + prow * 128;

    for (int k0 = 0; k0 < P_DIM; k0 += 64) {
        // ---- A: 4 f32x4 loads (issued first so the cvt below waits only on these)
        const float* ak = Arow + k0 + pseg * 16;
        float4 f0 = ((const float4*)ak)[0];
        float4 f1 = ((const float4*)ak)[1];
        float4 f2 = ((const float4*)ak)[2];
        float4 f3 = ((const float4*)ak)[3];
        // ---- B: 16 KB via global_load_lds (inverse-swizzled source, linear dest)
        #pragma unroll
        for (int r = 0; r < 4; ++r) {
            const int o2  = r * 4096 + w * 1024 + l * 16;   // 0..16384
            const int row = o2 >> 7;
            const int c   = (o2 >> 4) & 7;
            const char* g = Bbase + (size_t)row * (P_DIM * 2) + k0 * 2 + ((c ^ (row & 7)) << 4);
            __builtin_amdgcn_global_load_lds((gptr_t)g, (sptr_t)(lds + 8192 + r * 4096 + w * 1024), 16, 0, 0);
        }
        // ---- convert A to bf16 (scaled) and write swizzled
        alignas(16) __hip_bfloat16 tb[16];
        tb[0]  = __float2bfloat16(f0.x * scl); tb[1]  = __float2bfloat16(f0.y * scl);
        tb[2]  = __float2bfloat16(f0.z * scl); tb[3]  = __float2bfloat16(f0.w * scl);
        tb[4]  = __float2bfloat16(f1.x * scl); tb[5]  = __float2bfloat16(f1.y * scl);
        tb[6]  = __float2bfloat16(f1.z * scl); tb[7]  = __float2bfloat16(f1.w * scl);
        tb[8]  = __float2bfloat16(f2.x * scl); tb[9]  = __float2bfloat16(f2.y * scl);
        tb[10] = __float2bfloat16(f2.z * scl); tb[11] = __float2bfloat16(f2.w * scl);
        tb[12] = __float2bfloat16(f3.x * scl); tb[13] = __float2bfloat16(f3.y * scl);
        tb[14] = __float2bfloat16(f3.z * scl); tb[15] = __float2bfloat16(f3.w * scl);
        *(uint4*)(awr + sc0) = ((const uint4*)tb)[0];
        *(uint4*)(awr + sc1) = ((const uint4*)tb)[1];
        __syncthreads();   // drains vmcnt (B lds-loads) + lgkm (A ds_writes)

        // ---- two K=32 mfma sub-steps over the staged BK=64 tile
        #pragma unroll
        for (int s = 0; s < 2; ++s) {
            const int kb = s * 64 + q * 16;
            bf16x8 af[4], bfr[2];
            #pragma unroll
            for (int i = 0; i < 4; ++i) {
                const int m = i * 16 + m16;              // m&7 == m16&7
                af[i] = *(const bf16x8*)(lds + m * 128 + (kb ^ swz));
            }
            #pragma unroll
            for (int j = 0; j < 2; ++j) {
                const int nn = w * 32 + j * 16 + m16;    // nn&7 == m16&7
                bfr[j] = *(const bf16x8*)(lds + 8192 + nn * 128 + (kb ^ swz));
            }
            #pragma unroll
            for (int i = 0; i < 4; ++i)
                #pragma unroll
                for (int j = 0; j < 2; ++j)
                    acc[i][j] = __builtin_amdgcn_mfma_f32_16x16x32_bf16(af[i], bfr[j], acc[i][j], 0, 0, 0);
        }
        __syncthreads();
    }

    // ---- epilogue: out = 2*cross - x_sq[row] - m_sq[col]
    // C/D layout: col = lane&15, row = quad*4 + reg [verified m89/m91 + R2 pass]
    const int colbase = bcol * 128 + w * 32;
    float msq[2];
    #pragma unroll
    for (int j = 0; j < 2; ++j) {
        const int col = colbase + j * 16 + m16;
        msq[j] = (col < C_CLS) ? m_sq[col] : 0.0f;
    }
    #pragma unroll
    for (int i = 0; i < 4; ++i) {
        #pragma unroll
        for (int reg = 0; reg < 4; ++reg) {
            const int lrow = i * 16 + q * 4 + reg;
            const int row  = rowbase + lrow;
            const float xsq = xsq_lds[lrow];
            #pragma unroll
            for (int j = 0; j < 2; ++j) {
                const int col = colbase + j * 16 + m16;
                if (col < C_CLS) {
                    out[(size_t)row * C_CLS + col] = 2.0f * acc[i][j][reg] - xsq - msq[j];
                }
            }
        }
    }
}

// ---- launch ----------------------------------------------------------------
extern "C" void kernel_launch(void* const* d_in, const int* in_sizes, int n_in,
                              void* d_out, int out_size, void* d_ws, size_t ws_size,
                              hipStream_t stream) {
    const float* x     = (const float*)d_in[0];   // [8192][512]
    const float* means = (const float*)d_in[1];   // [1000][512]
    float* out = (float*)d_out;                   // [8192][1000]
    char* ws = (char*)d_ws;

    __hip_bfloat16* means_bf = (__hip_bfloat16*)(ws + WS_MEANS_BF);
    float*          m_sq     = (float*)(ws + WS_MSQ);

    prep_means<<<C_PAD / 4, 256, 0, stream>>>(means, means_bf, m_sq);
    gemm_k<<<1024, 256, 0, stream>>>(x, means_bf, m_sq, out);
}

// Round 3
// 92.697 us; speedup vs baseline: 1.1446x; 1.1446x over previous
//
#include <hip/hip_runtime.h>
#include <hip/hip_bf16.h>
#include <stdint.h>

// ---- types -----------------------------------------------------------------
typedef __bf16 bf16x8 __attribute__((ext_vector_type(8)));
typedef float  f32x4  __attribute__((ext_vector_type(4)));
typedef __attribute__((address_space(1))) const void* gptr_t;
typedef __attribute__((address_space(3))) void*       sptr_t;

#define B_ROWS 8192
#define C_CLS  1000
#define C_PAD  1024
#define P_DIM  512
#define EPS    1e-10f

// ---- workspace layout (bytes) ----------------------------------------------
// [0,            1048576)  means_bf16  [1024][512] bf16  (rows >=1000 zeroed)
// [1048576,      1052672)  m_sq        [1024] f32
// [1052672,      9441280)  xn_bf16     [8192][512] bf16
// [9441280,      9474048)  x_sq        [8192] f32
#define WS_MEANS_BF 0
#define WS_MSQ      1048576
#define WS_XN_BF    1052672
#define WS_XSQ      9441280

__device__ __forceinline__ float dot8(float4 a, float4 b) {
    return a.x * a.x + a.y * a.y + a.z * a.z + a.w * a.w
         + b.x * b.x + b.y * b.y + b.z * b.z + b.w * b.w;
}

// ---- kernel 1 (fused prep): blocks 0..2047 -> x rows; 2048..2303 -> means ---
// (identical to R1 -- R2's fusion of this into the gemm regressed 17 us:
//  per-block serial f32 X reads + VALU cvt in the K-loop critical path)
__global__ __launch_bounds__(256) void prep_k(const float* __restrict__ x,
                                              const float* __restrict__ means,
                                              __hip_bfloat16* __restrict__ means_bf,
                                              float* __restrict__ m_sq,
                                              __hip_bfloat16* __restrict__ xn_bf,
                                              float* __restrict__ x_sq) {
    const int w = threadIdx.x >> 6;
    const int l = threadIdx.x & 63;
    const int bid = blockIdx.x;

    if (bid < B_ROWS / 4) {
        // ---- x row: one wave per row
        const int row = bid * 4 + w;
        const float4* m0 = (const float4*)means;   // scale source, L2-hot
        float4 ma = m0[l * 2];
        float4 mb = m0[l * 2 + 1];
        float ms = dot8(ma, mb);
        const float4* xr = (const float4*)(x + (size_t)row * P_DIM);
        float4 a = xr[l * 2];
        float4 b = xr[l * 2 + 1];
        float s = dot8(a, b);
        #pragma unroll
        for (int off = 32; off > 0; off >>= 1) {
            ms += __shfl_down(ms, off);
            s  += __shfl_down(s, off);
        }
        ms = __shfl(ms, 0);
        s  = __shfl(s, 0);
        float scale = sqrtf(ms);               // ||means[0]||
        float norm  = sqrtf(s);
        float sc    = scale / (norm + EPS);
        alignas(16) __hip_bfloat16 tmp[8];
        tmp[0] = __float2bfloat16(a.x * sc); tmp[1] = __float2bfloat16(a.y * sc);
        tmp[2] = __float2bfloat16(a.z * sc); tmp[3] = __float2bfloat16(a.w * sc);
        tmp[4] = __float2bfloat16(b.x * sc); tmp[5] = __float2bfloat16(b.y * sc);
        tmp[6] = __float2bfloat16(b.z * sc); tmp[7] = __float2bfloat16(b.w * sc);
        *(uint4*)(xn_bf + (size_t)row * P_DIM + l * 8) = *(const uint4*)tmp;
        if (l == 0) {
            float sn = sc * norm;              // ||xn|| as the reference computes it
            x_sq[row] = sn * sn;
        }
    } else {
        // ---- means row: one wave per class (padded to 1024)
        const int c = (bid - B_ROWS / 4) * 4 + w;
        if (c < C_CLS) {
            const float4* mr = (const float4*)(means + (size_t)c * P_DIM);
            float4 a = mr[l * 2];
            float4 b = mr[l * 2 + 1];
            float s = dot8(a, b);
            alignas(16) __hip_bfloat16 tmp[8];
            tmp[0] = __float2bfloat16(a.x); tmp[1] = __float2bfloat16(a.y);
            tmp[2] = __float2bfloat16(a.z); tmp[3] = __float2bfloat16(a.w);
            tmp[4] = __float2bfloat16(b.x); tmp[5] = __float2bfloat16(b.y);
            tmp[6] = __float2bfloat16(b.z); tmp[7] = __float2bfloat16(b.w);
            *(uint4*)(means_bf + (size_t)c * P_DIM + l * 8) = *(const uint4*)tmp;
            #pragma unroll
            for (int off = 32; off > 0; off >>= 1) s += __shfl_down(s, off);
            if (l == 0) m_sq[c] = s;
        } else {
            uint4 z = {0u, 0u, 0u, 0u};
            *(uint4*)(means_bf + (size_t)c * P_DIM + l * 8) = z;
            if (l == 0) m_sq[c] = 0.0f;
        }
    }
}

// ---- kernel 2: logits = 2*(xn @ means^T) - x_sq - m_sq ---------------------
// 64x128 tile, 4 waves, grid 1024 (4 blocks/CU, exact one-pass fill), XCD
// remap (T1). R3 change: triple-buffered depth-2 pipeline (T3/T4 minimum):
//   BK=32, buffer = A[64][64B] (4 KB) + B[128][64B] (8 KB) = 12 KB; x3 = 36 KB
//   iter t: STAGE(buf[t+2], k=t+2) ; compute buf[t] ; vmcnt(3) ; s_barrier
// vmcnt accounting (3 loads/thread/stage): at the barrier of iter t the
// outstanding set is {t+1:3, t+2:3}; vmcnt(3) retires exactly the t+1 buffer
// (needed next iter) and keeps t+2's loads in flight ACROSS the barrier --
// never drains to 0 in the main loop (the R1 structure's ~full-latency stall).
// Layout is linear, NO swizzle: with 64-B rows the b128 wave-read is already
// bank-balanced (even rows -> banks 0-15, odd -> 16-31; 32 B/bank/instr =
// the 8-cycle minimum for 1 KB). The R1 swizzle was only needed for 128-B rows.
#define GEMM_STAGE(sbase, k0)                                                              \
    do {                                                                                   \
        {   /* A: 4 KB, one round */                                                       \
            const int o = w * 1024 + l * 16;                                               \
            const char* g = Abase + (size_t)(o >> 6) * (P_DIM * 2) + (k0) * 2 + (o & 63);  \
            __builtin_amdgcn_global_load_lds((gptr_t)g, (sptr_t)(lds + (sbase) + w * 1024), 16, 0, 0); \
        }                                                                                  \
        _Pragma("unroll")                                                                  \
        for (int r = 0; r < 2; ++r) {   /* B: 8 KB, two rounds */                          \
            const int o2 = r * 4096 + w * 1024 + l * 16;                                   \
            const char* g = Bbase + (size_t)(o2 >> 6) * (P_DIM * 2) + (k0) * 2 + (o2 & 63);\
            __builtin_amdgcn_global_load_lds((gptr_t)g, (sptr_t)(lds + (sbase) + 4096 + r * 4096 + w * 1024), 16, 0, 0); \
        }                                                                                  \
    } while (0)

__global__ __launch_bounds__(256, 4) void gemm_k(const __hip_bfloat16* __restrict__ A,   // xn   [8192][512]
                                                 const __hip_bfloat16* __restrict__ B,   // means[1024][512]
                                                 const float* __restrict__ x_sq,
                                                 const float* __restrict__ m_sq,
                                                 float* __restrict__ out) {
    __shared__ alignas(16) char lds[36864];     // 3 x 12 KB
    const int t   = threadIdx.x;
    const int w   = t >> 6;         // wave 0..3
    const int l   = t & 63;
    const int q   = l >> 4;         // quad 0..3
    const int m16 = l & 15;

    // XCD-aware remap: n%8 = XCD; each XCD owns 16 consecutive brows x all
    // bcols -> per-XCD L2 set = 1 MB A-slice + 1 MB B (resident).
    const int n_blk  = blockIdx.x;            // 0..1023
    const int xcd    = n_blk & 7;
    const int within = n_blk >> 3;            // 0..127
    const int brow   = xcd * 16 + (within & 15);   // 0..127 (64-row tiles)
    const int bcol   = within >> 4;                // 0..7   (128-col tiles)

    f32x4 acc[4][2];
    #pragma unroll
    for (int i = 0; i < 4; ++i)
        #pragma unroll
        for (int j = 0; j < 2; ++j) {
            f32x4 z = {0.f, 0.f, 0.f, 0.f};
            acc[i][j] = z;
        }

    const char* Abase = (const char*)A + (size_t)(brow * 64)  * (P_DIM * 2);
    const char* Bbase = (const char*)B + (size_t)(bcol * 128) * (P_DIM * 2);

    // ---- prologue: stage k-steps 0 and 1; retire buffer 0 (keep 1 in flight)
    GEMM_STAGE(0, 0);
    GEMM_STAGE(12288, 32);
    asm volatile("s_waitcnt vmcnt(3)" ::: "memory");
    __builtin_amdgcn_s_barrier();
    asm volatile("" ::: "memory");              // no code motion above the barrier

    int cur = 0;            // byte base of the buffer computed this iter (t%3)
    int stg = 24576;        // byte base of the buffer staged this iter ((t+2)%3)

    for (int kt = 0; kt < 16; ++kt) {
        if (kt < 14) GEMM_STAGE(stg, (kt + 2) * 32);

        const char* cb = lds + cur;
        bf16x8 af[4], bfr[2];
        #pragma unroll
        for (int i = 0; i < 4; ++i) {
            const int m = i * 16 + m16;
            af[i] = *(const bf16x8*)(cb + m * 64 + q * 16);
        }
        #pragma unroll
        for (int j = 0; j < 2; ++j) {
            const int nn = w * 32 + j * 16 + m16;
            bfr[j] = *(const bf16x8*)(cb + 4096 + nn * 64 + q * 16);
        }
        #pragma unroll
        for (int i = 0; i < 4; ++i)
            #pragma unroll
            for (int j = 0; j < 2; ++j)
                acc[i][j] = __builtin_amdgcn_mfma_f32_16x16x32_bf16(af[i], bfr[j], acc[i][j], 0, 0, 0);

        if (kt < 15) {
            // retire the k(t+1) buffer's 3 loads; keep k(t+2)'s in flight.
            if (kt < 14) asm volatile("s_waitcnt vmcnt(3)" ::: "memory");
            else         asm volatile("s_waitcnt vmcnt(0)" ::: "memory");
            __builtin_amdgcn_s_barrier();
            asm volatile("" ::: "memory");      // keep next iter's ds_reads below
        }
        cur = (cur == 24576) ? 0 : cur + 12288;
        stg = (stg == 24576) ? 0 : stg + 12288;
    }

    // ---- epilogue: out = 2*cross - x_sq[row] - m_sq[col]
    // C/D layout: col = lane&15, row = quad*4 + reg [verified m89/m91 + R2 pass]
    const int rowbase = brow * 64;
    const int colbase = bcol * 128 + w * 32;
    float msq[2];
    #pragma unroll
    for (int j = 0; j < 2; ++j) {
        const int col = colbase + j * 16 + m16;
        msq[j] = (col < C_CLS) ? m_sq[col] : 0.0f;
    }
    #pragma unroll
    for (int i = 0; i < 4; ++i) {
        #pragma unroll
        for (int reg = 0; reg < 4; ++reg) {
            const int row = rowbase + i * 16 + q * 4 + reg;
            const float xsq = x_sq[row];
            #pragma unroll
            for (int j = 0; j < 2; ++j) {
                const int col = colbase + j * 16 + m16;
                if (col < C_CLS) {
                    out[(size_t)row * C_CLS + col] = 2.0f * acc[i][j][reg] - xsq - msq[j];
                }
            }
        }
    }
}

// ---- launch ----------------------------------------------------------------
extern "C" void kernel_launch(void* const* d_in, const int* in_sizes, int n_in,
                              void* d_out, int out_size, void* d_ws, size_t ws_size,
                              hipStream_t stream) {
    const float* x     = (const float*)d_in[0];   // [8192][512]
    const float* means = (const float*)d_in[1];   // [1000][512]
    float* out = (float*)d_out;                   // [8192][1000]
    char* ws = (char*)d_ws;

    __hip_bfloat16* means_bf = (__hip_bfloat16*)(ws + WS_MEANS_BF);
    float*          m_sq     = (float*)(ws + WS_MSQ);
    __hip_bfloat16* xn_bf    = (__hip_bfloat16*)(ws + WS_XN_BF);
    float*          x_sq     = (float*)(ws + WS_XSQ);

    prep_k<<<B_ROWS / 4 + C_PAD / 4, 256, 0, stream>>>(x, means, means_bf, m_sq, xn_bf, x_sq);
    gemm_k<<<1024, 256, 0, stream>>>(xn_bf, means_bf, x_sq, m_sq, out);
}